// Round 7
// baseline (474.580 us; speedup 1.0000x reference)
//
#include <hip/hip_runtime.h>
#include <stdint.h>

#define N_NODES 50000
#define E_EDGES 800000
#define HID 128
#define NG16 50000             // E_EDGES / 16 (edge-groups per grid-stride loop)
#define BE 128                 // edges per block (fallback kernel)
#define XS_STRIDE 264
#define YS_STRIDE 136
#define HS_STRIDE 132          // 66 words ≡ 2 mod 32 -> 2-way (free) A reads
#define CB_STRIDE 264          // u16 C-stage stride; row*132w ≡ 4*row mod 32 -> spread banks

typedef unsigned short u16;
typedef unsigned char u8;
typedef __attribute__((ext_vector_type(8))) short svec8;
typedef __attribute__((ext_vector_type(16))) float fvec16;
typedef __attribute__((ext_vector_type(4))) float fvec4;
typedef __attribute__((ext_vector_type(4))) unsigned uvec4;
typedef __attribute__((ext_vector_type(2))) unsigned uvec2;
typedef __attribute__((ext_vector_type(2))) float fvec2;

union frag_u { unsigned u[4]; svec8 s; };

__device__ __forceinline__ float bf2f(u16 u) {
    union { unsigned int i; float f; } v; v.i = ((unsigned int)u) << 16; return v.f;
}
__device__ __forceinline__ u16 f2bf(float f) {
    union { float f; unsigned int i; } v; v.f = f;
    unsigned int u = v.i;
    return (u16)((u + 0x7fffu + ((u >> 16) & 1u)) >> 16);   // RNE
}
__device__ __forceinline__ unsigned f2u(float f) {
    union { float f; unsigned i; } v; v.f = f; return v.i;
}
__device__ __forceinline__ float lo16(unsigned u) {
    union { unsigned i; float f; } v; v.i = u << 16; return v.f;
}
__device__ __forceinline__ float hi16(unsigned u) {
    union { unsigned i; float f; } v; v.i = u & 0xFFFF0000u; return v.f;
}
__device__ __forceinline__ float silu_f(float x) {
    return x * __builtin_amdgcn_rcpf(1.0f + __expf(-x));
}
__device__ __forceinline__ float ldf(const void* p, size_t i, int is_bf) {
    return is_bf ? bf2f(((const u16*)p)[i]) : ((const float*)p)[i];
}
__device__ __forceinline__ int ldi(const void* p, size_t i, int is_i64) {
    return is_i64 ? ((const int*)p)[2 * i] : ((const int*)p)[i];
}

// ---- dtype detection: flags[0]=floats-are-bf16, flags[1]=edge_index-is-int64 ----
__global__ void detect_kernel(const void* __restrict__ h,
                              const void* __restrict__ eidx,
                              int* __restrict__ flags) {
    __shared__ int cnt_bf, cnt_i64;
    if (threadIdx.x == 0) { cnt_bf = 0; cnt_i64 = 0; }
    __syncthreads();
    const int t = threadIdx.x;
    unsigned u = ((const u16*)h)[2 * t];
    unsigned e = (u >> 7) & 0xFFu;
    int plaus = (e >= 100u && e <= 140u) ? 1 : 0;
    int z = (((const int*)eidx)[2 * t + 1] == 0) ? 1 : 0;
    atomicAdd(&cnt_bf, plaus);
    atomicAdd(&cnt_i64, z);
    __syncthreads();
    if (t == 0) { flags[0] = (cnt_bf >= 128); flags[1] = (cnt_i64 >= 128); }
}

// ---- W transpose + w1l(bf16): W1[257][128]->W1t[128][256], W2->W2t, W1[256][:]->w1lb ----
__global__ void transpose_w(const void* __restrict__ W1, const void* __restrict__ W2,
                            u16* __restrict__ W1t, u16* __restrict__ W2t,
                            u16* __restrict__ w1lb, const int* __restrict__ flags) {
    const int is_bf = flags[0];
    int n = blockIdx.x;        // 0..127 output column
    int k = threadIdx.x;       // 0..255
    W1t[n * 256 + k] = f2bf(ldf(W1, (size_t)k * 128 + n, is_bf));
    if (k < 128) W2t[n * 128 + k] = f2bf(ldf(W2, (size_t)k * 128 + n, is_bf));
    if (n == 0 && k < 128) w1lb[k] = f2bf(ldf(W1, (size_t)256 * 128 + k, is_bf));
}

// ---- precompute P[node][0:128]=fp8(h@W1a+b1), P[node][128:256]=fp8(h@W1b) ----
// C staged as bf16 (67.6 KB union, was 128 KB f32) -> 2 blocks/CU instead of 1.
__global__ __launch_bounds__(256) void precompute_p(
    const void* __restrict__ h, const void* __restrict__ b1,
    const u16* __restrict__ W1t, const int* __restrict__ flags,
    u8* __restrict__ P)
{
    __shared__ __align__(16) union SMem {
        u16 Hs[128 * HS_STRIDE];       // 33.8 KB
        u16 Cb[128 * CB_STRIDE];       // 67.6 KB
    } sm;
    const int tid = threadIdx.x;
    const int is_bf = flags[0];
    const int base = blockIdx.x * 128;
    {
        const int rr = tid >> 5, c = tid & 31;
        for (int it = 0; it < 16; ++it) {
            int row = it * 8 + rr;
            int node = base + row; if (node > N_NODES - 1) node = N_NODES - 1;
            u16* dst = &sm.Hs[row * HS_STRIDE + c * 4];
            if (is_bf) {
                *(uint2*)dst = *(const uint2*)((const u16*)h + (size_t)node * HID + c * 4);
            } else {
                float4 v = *(const float4*)((const float*)h + (size_t)node * HID + c * 4);
                uint2 w;
                w.x = (unsigned)f2bf(v.x) | ((unsigned)f2bf(v.y) << 16);
                w.y = (unsigned)f2bf(v.z) | ((unsigned)f2bf(v.w) << 16);
                *(uint2*)dst = w;
            }
        }
    }
    __syncthreads();
    const int lane = tid & 63, wv = tid >> 6, l31 = lane & 31, hi = lane >> 5;
    // wave wv: rows [wv*32, wv*32+32) x all 256 output cols (8 strips)
    fvec16 acc[8] = {};
    for (int ks = 0; ks < 8; ++ks) {
        const int kk = ks * 16 + hi * 8;
        svec8 af = *(const svec8*)(&sm.Hs[(wv * 32 + l31) * HS_STRIDE + kk]);
        #pragma unroll
        for (int t = 0; t < 8; ++t) {
            const int n = t * 32 + l31;
            const u16* bp = (t < 4) ? (W1t + n * 256 + kk)
                                    : (W1t + (n - 128) * 256 + 128 + kk);
            svec8 bf = *(const svec8*)bp;
            acc[t] = __builtin_amdgcn_mfma_f32_32x32x16_bf16(af, bf, acc[t], 0, 0, 0);
        }
    }
    __syncthreads();                 // all waves done reading Hs before Cb overwrite
    #pragma unroll
    for (int t = 0; t < 8; ++t) {
        const int n = t * 32 + l31;
        const float bias = (t < 4) ? ldf(b1, n, is_bf) : 0.0f;
        #pragma unroll
        for (int r = 0; r < 16; ++r) {
            int m = (r & 3) + 8 * (r >> 2) + 4 * hi;
            sm.Cb[(wv * 32 + m) * CB_STRIDE + n] = f2bf(acc[t][r] + bias);
        }
    }
    __syncthreads();
    // pack fp8 + coalesced 16B stores: 16 threads per node row
    #pragma unroll
    for (int i = 0; i < 8; ++i) {
        int row = i * 16 + (tid >> 4);
        int node = base + row;
        if (node < N_NODES) {
            const u16* src = &sm.Cb[row * CB_STRIDE + (tid & 15) * 16];
            uint4 w0 = *(const uint4*)src;
            uint4 w1 = *(const uint4*)(src + 8);
            unsigned wd[8] = {w0.x, w0.y, w0.z, w0.w, w1.x, w1.y, w1.z, w1.w};
            uvec4 outv;
            #pragma unroll
            for (int j = 0; j < 4; ++j) {
                int q = __builtin_amdgcn_cvt_pk_fp8_f32(lo16(wd[2 * j]), hi16(wd[2 * j]), 0, false);
                q     = __builtin_amdgcn_cvt_pk_fp8_f32(lo16(wd[2 * j + 1]), hi16(wd[2 * j + 1]), q, true);
                outv[j] = (unsigned)q;
            }
            *(uvec4*)(P + (size_t)node * 256 + (tid & 15) * 16) = outv;
        }
    }
}

// ---- edge kernel v2: 16x16x32 MFMA, 16 edges/wave-iter, acc=32 AGPR, coefs in LDS ----
// Target: total VGPR+AGPR <= 128 -> 4 waves/SIMD (round 4/6 plateaued at 2: 128 arch
// + 64 AGPR = 192/wave). (256,4) = total cap 128; round-5 spill was demand ~192 vs cap.
__global__ __launch_bounds__(256, 4) void egnn_edge_p2(
    const u8* __restrict__ P, const void* __restrict__ coord_diff,
    const void* __restrict__ edge_attr, const void* __restrict__ edge_index,
    const u16* __restrict__ w1lb, const void* __restrict__ b2,
    const void* __restrict__ W3, const u16* __restrict__ W2t,
    float* __restrict__ agg, const int* __restrict__ flags)
{
    __shared__ __align__(16) u16 W2f[16384];   // 32 KB: chunk f=(t*4+s)*64+lane, 8 u16 each
    __shared__ float w1s[128];
    __shared__ float b2s[128];
    __shared__ float w3s[128];
    const int tid = threadIdx.x;
    const int is_bf = flags[0], is_i64 = flags[1];
    // stage W2 fragments: B[k][n] for 16x16x32, lane=(n=ln&15, kg=ln>>4), k=s*32+kg*8+j
    #pragma unroll
    for (int i = 0; i < 8; ++i) {
        int f = i * 256 + tid;
        int t = f >> 8, s = (f >> 6) & 3, ln = f & 63;
        int n = t * 16 + (ln & 15), kg = ln >> 4;
        *(svec8*)(&W2f[f * 8]) = *(const svec8*)(W2t + n * 128 + s * 32 + kg * 8);
    }
    if (tid < 128) {
        w1s[tid] = bf2f(w1lb[tid]);
        b2s[tid] = ldf(b2, tid, is_bf);
        w3s[tid] = ldf(W3, tid, is_bf);
    }
    __syncthreads();                           // last barrier; main loop is wave-autonomous

    const int lane = tid & 63, wv = tid >> 6;
    const int m = lane & 15, kg = lane >> 4;   // edge-in-group, k-group
    const int wid = blockIdx.x * 4 + wv, nw = gridDim.x * 4;

    for (int g = wid; g < NG16; g += nw) {
        const int e   = g * 16 + m;
        const int row = ldi(edge_index, (size_t)e, is_i64);
        const int col = ldi(edge_index, (size_t)E_EDGES + e, is_i64);
        const float ea = ldf(edge_attr, (size_t)e, is_bf);
        const u8* pr = P + (size_t)row * 256 + kg * 8;
        const u8* pc = P + (size_t)col * 256 + 128 + kg * 8;

        uvec2 p1[4], p2[4];
        #pragma unroll
        for (int s = 0; s < 4; ++s) {
            p1[s] = *(const uvec2*)(pr + s * 32);
            p2[s] = *(const uvec2*)(pc + s * 32);
        }

        fvec4 acc[8] = {};
        #pragma unroll
        for (int s = 0; s < 4; ++s) {
            const int k0 = s * 32 + kg * 8;
            float4 wla = *(const float4*)(&w1s[k0]);
            float4 wlb = *(const float4*)(&w1s[k0 + 4]);
            frag_u af;
            #pragma unroll
            for (int d = 0; d < 2; ++d) {
                fvec2 a01 = __builtin_amdgcn_cvt_pk_f32_fp8((int)p1[s][d], false);
                fvec2 a23 = __builtin_amdgcn_cvt_pk_f32_fp8((int)p1[s][d], true);
                fvec2 b01 = __builtin_amdgcn_cvt_pk_f32_fp8((int)p2[s][d], false);
                fvec2 b23 = __builtin_amdgcn_cvt_pk_f32_fp8((int)p2[s][d], true);
                const float* wl = d ? &wlb.x : &wla.x;
                float x0 = a01[0] + b01[0] + ea * wl[0];
                float x1 = a01[1] + b01[1] + ea * wl[1];
                float x2 = a23[0] + b23[0] + ea * wl[2];
                float x3 = a23[1] + b23[1] + ea * wl[3];
                float y0 = silu_f(x0), y1 = silu_f(x1);
                float y2 = silu_f(x2), y3 = silu_f(x3);
                af.u[d * 2 + 0] = (f2u(y0) >> 16) | (f2u(y1) & 0xFFFF0000u);
                af.u[d * 2 + 1] = (f2u(y2) >> 16) | (f2u(y3) & 0xFFFF0000u);
            }
            #pragma unroll
            for (int t = 0; t < 8; ++t) {
                svec8 bf = *(const svec8*)(&W2f[((t * 4 + s) * 64 + lane) * 8]);
                acc[t] = __builtin_amdgcn_mfma_f32_16x16x32_bf16(af.s, bf, acc[t], 0, 0, 0);
            }
        }
        // epilogue: C layout col=lane&15(=n offset), row=kg*4+r(=edge in group)
        float s4[4] = {0.0f, 0.0f, 0.0f, 0.0f};
        #pragma unroll
        for (int t = 0; t < 8; ++t) {
            const float bb = b2s[t * 16 + m];
            const float ww = w3s[t * 16 + m];
            #pragma unroll
            for (int r = 0; r < 4; ++r)
                s4[r] += silu_f(acc[t][r] + bb) * ww;
        }
        #pragma unroll
        for (int r = 0; r < 4; ++r) {          // sum over the 16-lane col group
            s4[r] += __shfl_xor(s4[r], 1);
            s4[r] += __shfl_xor(s4[r], 2);
            s4[r] += __shfl_xor(s4[r], 4);
            s4[r] += __shfl_xor(s4[r], 8);
        }
        if (m < 4) {                           // lane kg*16+r handles edge g*16+kg*4+r
            const float phi = s4[m];
            const int eg = g * 16 + kg * 4 + m;
            const int r2 = ldi(edge_index, (size_t)eg, is_i64);
            const float cx = ldf(coord_diff, (size_t)eg * 3 + 0, is_bf);
            const float cy = ldf(coord_diff, (size_t)eg * 3 + 1, is_bf);
            const float cz = ldf(coord_diff, (size_t)eg * 3 + 2, is_bf);
            atomicAdd(&agg[r2 * 3 + 0], cx * phi);
            atomicAdd(&agg[r2 * 3 + 1], cy * phi);
            atomicAdd(&agg[r2 * 3 + 2], cz * phi);
        }
    }
}

// ================= fallback (round-3, verified) when ws too small =================
__global__ __launch_bounds__(256, 2) void egnn_edge_kernel(
    const void* __restrict__ h, const void* __restrict__ coord_diff,
    const void* __restrict__ edge_attr, const void* __restrict__ edge_index,
    const void* __restrict__ W1, const void* __restrict__ b1,
    const void* __restrict__ b2, const void* __restrict__ W3,
    const u16* __restrict__ W1t, const u16* __restrict__ W2t,
    float* __restrict__ agg, const int* __restrict__ flags)
{
    __shared__ __align__(16) u16 Xs[BE * XS_STRIDE];
    __shared__ int   rows_s[BE];
    __shared__ int   cols_s[BE];
    __shared__ float ea_s[BE];
    __shared__ float b1_s[HID], b2_s[HID], w1l_s[HID], w3_s[HID];

    const int tid = threadIdx.x;
    const int e0  = blockIdx.x * BE;
    const int is_bf  = flags[0];
    const int is_i64 = flags[1];

    if (tid < BE) {
        rows_s[tid] = ldi(edge_index, (size_t)(e0 + tid), is_i64);
        cols_s[tid] = ldi(edge_index, (size_t)(E_EDGES + e0 + tid), is_i64);
        ea_s[tid]   = ldf(edge_attr, (size_t)(e0 + tid), is_bf);
    }
    if (tid < HID) {
        b1_s[tid]  = ldf(b1, tid, is_bf);
        b2_s[tid]  = ldf(b2, tid, is_bf);
        w1l_s[tid] = ldf(W1, (size_t)256 * 128 + tid, is_bf);
        w3_s[tid]  = ldf(W3, tid, is_bf);
    }
    __syncthreads();
    {
        const int gg = tid >> 4, c = tid & 15;
        #pragma unroll
        for (int it = 0; it < 16; ++it) {
            int hr = it * 16 + gg;
            int e = hr >> 1, half = hr & 1;
            int src = half ? cols_s[e] : rows_s[e];
            svec8 v;
            if (is_bf) {
                v = *(const svec8*)((const u16*)h + (size_t)src * HID + c * 8);
            } else {
                const float* hf = (const float*)h + (size_t)src * HID + c * 8;
                float4 va = *(const float4*)hf;
                float4 vb = *(const float4*)(hf + 4);
                v[0] = (short)f2bf(va.x); v[1] = (short)f2bf(va.y);
                v[2] = (short)f2bf(va.z); v[3] = (short)f2bf(va.w);
                v[4] = (short)f2bf(vb.x); v[5] = (short)f2bf(vb.y);
                v[6] = (short)f2bf(vb.z); v[7] = (short)f2bf(vb.w);
            }
            *(svec8*)(&Xs[e * XS_STRIDE + half * 128 + c * 8]) = v;
        }
    }
    __syncthreads();
    const int lane = tid & 63;
    const int wv   = tid >> 6;
    const int l31  = lane & 31, hi = lane >> 5;
    const int col  = wv * 32 + l31;

    fvec16 acc[4] = {};
    for (int ks = 0; ks < 16; ++ks) {
        const int kk = ks * 16 + hi * 8;
        svec8 bfrag = *(const svec8*)(W1t + col * 256 + kk);
        #pragma unroll
        for (int mt = 0; mt < 4; ++mt) {
            svec8 afrag = *(const svec8*)(&Xs[(mt * 32 + l31) * XS_STRIDE + kk]);
            acc[mt] = __builtin_amdgcn_mfma_f32_32x32x16_bf16(afrag, bfrag, acc[mt], 0, 0, 0);
        }
    }
    __syncthreads();
    u16* Ys = Xs;
    #pragma unroll
    for (int mt = 0; mt < 4; ++mt)
        #pragma unroll
        for (int r = 0; r < 16; ++r) {
            int row = mt * 32 + (r & 3) + 8 * (r >> 2) + 4 * hi;
            float v = acc[mt][r] + ea_s[row] * w1l_s[col] + b1_s[col];
            Ys[row * YS_STRIDE + col] = f2bf(silu_f(v));
        }
    __syncthreads();
    fvec16 acc2[4] = {};
    for (int ks = 0; ks < 8; ++ks) {
        const int kk = ks * 16 + hi * 8;
        svec8 bfrag = *(const svec8*)(W2t + col * 128 + kk);
        #pragma unroll
        for (int mt = 0; mt < 4; ++mt) {
            svec8 afrag = *(const svec8*)(&Ys[(mt * 32 + l31) * YS_STRIDE + kk]);
            acc2[mt] = __builtin_amdgcn_mfma_f32_32x32x16_bf16(afrag, bfrag, acc2[mt], 0, 0, 0);
        }
    }
    __syncthreads();
    #pragma unroll
    for (int mt = 0; mt < 4; ++mt)
        #pragma unroll
        for (int r = 0; r < 16; ++r) {
            int row = mt * 32 + (r & 3) + 8 * (r >> 2) + 4 * hi;
            float v = acc2[mt][r] + b2_s[col];
            Ys[row * YS_STRIDE + col] = f2bf(silu_f(v));
        }
    __syncthreads();
    if (tid < BE) {
        const int e = tid;
        float phi = 0.0f;
        #pragma unroll
        for (int j = 0; j < 16; ++j) {
            svec8 x = *(const svec8*)(&Ys[e * YS_STRIDE + j * 8]);
            #pragma unroll
            for (int t = 0; t < 8; ++t)
                phi += bf2f((u16)x[t]) * w3_s[j * 8 + t];
        }
        const size_t ei = (size_t)(e0 + e);
        const int r = rows_s[e];
        atomicAdd(&agg[r * 3 + 0], ldf(coord_diff, ei * 3 + 0, is_bf) * phi);
        atomicAdd(&agg[r * 3 + 1], ldf(coord_diff, ei * 3 + 1, is_bf) * phi);
        atomicAdd(&agg[r * 3 + 2], ldf(coord_diff, ei * 3 + 2, is_bf) * phi);
    }
}

// ---- finalize: out = coord + agg/100, written in the input float dtype ----
__global__ void finalize_kernel(const void* __restrict__ coord,
                                const float* __restrict__ agg,
                                void* __restrict__ out,
                                const int* __restrict__ flags) {
    const int is_bf = flags[0];
    int i = blockIdx.x * blockDim.x + threadIdx.x;
    if (i < N_NODES * 3) {
        float v = ldf(coord, i, is_bf) + agg[i] * 0.01f;
        if (is_bf) ((u16*)out)[i] = f2bf(v);
        else       ((float*)out)[i] = v;
    }
}

extern "C" void kernel_launch(void* const* d_in, const int* in_sizes, int n_in,
                              void* d_out, int out_size, void* d_ws, size_t ws_size,
                              hipStream_t stream) {
    const void* h          = d_in[0];
    const void* coord      = d_in[1];
    const void* coord_diff = d_in[2];
    // d_in[3] = coord_cross (unused)
    const void* edge_attr  = d_in[4];
    const void* edge_index = d_in[5];
    const void* W1 = d_in[6];
    const void* b1 = d_in[7];
    const void* W2 = d_in[8];
    const void* b2 = d_in[9];
    const void* W3 = d_in[10];

    char* ws    = (char*)d_ws;
    float* agg  = (float*)ws;                        // 600000 B
    u16* W1t    = (u16*)(ws + 600064);               // 65536 B
    u16* W2t    = (u16*)(ws + 665600);               // 32768 B
    int* flags  = (int*)(ws + 698368);               // 16 B
    u16* w1lb   = (u16*)(ws + 698432);               // 256 B
    u8* P       = (u8*)(ws + 698880);                // 12,800,000 B (fp8)
    const size_t NEED = 698880 + (size_t)N_NODES * 256;

    detect_kernel<<<dim3(1), dim3(256), 0, stream>>>(h, edge_index, flags);
    hipMemsetAsync(agg, 0, N_NODES * 3 * sizeof(float), stream);
    transpose_w<<<dim3(128), dim3(256), 0, stream>>>(W1, W2, W1t, W2t, w1lb, flags);

    if (ws_size >= NEED) {
        precompute_p<<<dim3((N_NODES + 127) / 128), dim3(256), 0, stream>>>(
            h, b1, W1t, flags, P);
        egnn_edge_p2<<<dim3(1024), dim3(256), 0, stream>>>(
            P, coord_diff, edge_attr, edge_index, w1lb, b2, W3, W2t, agg, flags);
    } else {
        egnn_edge_kernel<<<dim3(E_EDGES / BE), dim3(256), 0, stream>>>(
            h, coord_diff, edge_attr, edge_index, W1, b1, b2, W3, W1t, W2t, agg, flags);
    }
    finalize_kernel<<<dim3((N_NODES * 3 + 255) / 256), dim3(256), 0, stream>>>(coord, agg, d_out, flags);
}

// Round 8
// 340.004 us; speedup vs baseline: 1.3958x; 1.3958x over previous
//
#include <hip/hip_runtime.h>
#include <stdint.h>

#define N_NODES 50000
#define E_EDGES 800000
#define HID 128
#define NG16 50000             // E_EDGES / 16
#define BE 128                 // edges per block (fallback kernel)
#define XS_STRIDE 264
#define YS_STRIDE 136
#define HS_STRIDE 132          // 66 words ≡ 2 mod 32 -> 2-way (free) A reads

typedef unsigned short u16;
typedef unsigned char u8;
typedef __attribute__((ext_vector_type(8))) short svec8;
typedef __attribute__((ext_vector_type(16))) float fvec16;
typedef __attribute__((ext_vector_type(4))) float fvec4;
typedef __attribute__((ext_vector_type(4))) unsigned uvec4;
typedef __attribute__((ext_vector_type(2))) unsigned uvec2;
typedef __attribute__((ext_vector_type(2))) float fvec2;

union frag_u { unsigned u[4]; svec8 s; };
union pk8_u { u16 h[8]; svec8 s; };

__device__ __forceinline__ float bf2f(u16 u) {
    union { unsigned int i; float f; } v; v.i = ((unsigned int)u) << 16; return v.f;
}
__device__ __forceinline__ u16 f2bf(float f) {
    union { float f; unsigned int i; } v; v.f = f;
    unsigned int u = v.i;
    return (u16)((u + 0x7fffu + ((u >> 16) & 1u)) >> 16);   // RNE
}
__device__ __forceinline__ unsigned f2u(float f) {
    union { float f; unsigned i; } v; v.f = f; return v.i;
}
__device__ __forceinline__ float lo16(unsigned u) {
    union { unsigned i; float f; } v; v.i = u << 16; return v.f;
}
__device__ __forceinline__ float hi16(unsigned u) {
    union { unsigned i; float f; } v; v.i = u & 0xFFFF0000u; return v.f;
}
__device__ __forceinline__ float silu_f(float x) {
    return x * __builtin_amdgcn_rcpf(1.0f + __expf(-x));
}
__device__ __forceinline__ float ldf(const void* p, size_t i, int is_bf) {
    return is_bf ? bf2f(((const u16*)p)[i]) : ((const float*)p)[i];
}
__device__ __forceinline__ int ldi(const void* p, size_t i, int is_i64) {
    return is_i64 ? ((const int*)p)[2 * i] : ((const int*)p)[i];
}

// ---- dtype detection: flags[0]=floats-are-bf16, flags[1]=edge_index-is-int64 ----
__global__ void detect_kernel(const void* __restrict__ h,
                              const void* __restrict__ eidx,
                              int* __restrict__ flags) {
    __shared__ int cnt_bf, cnt_i64;
    if (threadIdx.x == 0) { cnt_bf = 0; cnt_i64 = 0; }
    __syncthreads();
    const int t = threadIdx.x;
    unsigned u = ((const u16*)h)[2 * t];
    unsigned e = (u >> 7) & 0xFFu;
    int plaus = (e >= 100u && e <= 140u) ? 1 : 0;
    int z = (((const int*)eidx)[2 * t + 1] == 0) ? 1 : 0;
    atomicAdd(&cnt_bf, plaus);
    atomicAdd(&cnt_i64, z);
    __syncthreads();
    if (t == 0) { flags[0] = (cnt_bf >= 128); flags[1] = (cnt_i64 >= 128); }
}

// ---- W transpose: W1[257][128]->W1t[128][256] bf16, W2[128][128]->W2t ----
__global__ void transpose_w(const void* __restrict__ W1, const void* __restrict__ W2,
                            u16* __restrict__ W1t, u16* __restrict__ W2t,
                            const int* __restrict__ flags) {
    const int is_bf = flags[0];
    int n = blockIdx.x;        // 0..127 output column
    int k = threadIdx.x;       // 0..255
    W1t[n * 256 + k] = f2bf(ldf(W1, (size_t)k * 128 + n, is_bf));
    if (k < 128) W2t[n * 128 + k] = f2bf(ldf(W2, (size_t)k * 128 + n, is_bf));
}

// ---- precompute: P[node] = fp8, k-PERMUTED: byte l31*4+s holds feature s*32+l31 ----
// Direct register->global pack: no C-stage LDS, one barrier, coalesced dword stores.
__global__ __launch_bounds__(256) void precompute_p(
    const void* __restrict__ h, const void* __restrict__ b1,
    const u16* __restrict__ W1t, const int* __restrict__ flags,
    u8* __restrict__ P)
{
    __shared__ __align__(16) u16 Hs[128 * HS_STRIDE];   // 33.8 KB
    const int tid = threadIdx.x;
    const int is_bf = flags[0];
    const int base = blockIdx.x * 128;
    {
        const int rr = tid >> 5, c = tid & 31;
        for (int it = 0; it < 16; ++it) {
            int row = it * 8 + rr;
            int node = base + row; if (node > N_NODES - 1) node = N_NODES - 1;
            u16* dst = &Hs[row * HS_STRIDE + c * 4];
            if (is_bf) {
                *(uint2*)dst = *(const uint2*)((const u16*)h + (size_t)node * HID + c * 4);
            } else {
                float4 v = *(const float4*)((const float*)h + (size_t)node * HID + c * 4);
                uint2 w;
                w.x = (unsigned)f2bf(v.x) | ((unsigned)f2bf(v.y) << 16);
                w.y = (unsigned)f2bf(v.z) | ((unsigned)f2bf(v.w) << 16);
                *(uint2*)dst = w;
            }
        }
    }
    __syncthreads();
    const int lane = tid & 63, wv = tid >> 6, l31 = lane & 31, hi = lane >> 5;
    float b1v[4];
    #pragma unroll
    for (int s = 0; s < 4; ++s) b1v[s] = ldf(b1, s * 32 + l31, is_bf);
    // wave wv: rows [wv*32, wv*32+32) x all 256 output cols (8 strips)
    fvec16 acc[8] = {};
    for (int ks = 0; ks < 8; ++ks) {
        const int kk = ks * 16 + hi * 8;
        svec8 af = *(const svec8*)(&Hs[(wv * 32 + l31) * HS_STRIDE + kk]);
        #pragma unroll
        for (int t = 0; t < 8; ++t) {
            const int n = t * 32 + l31;
            const u16* bp = (t < 4) ? (W1t + n * 256 + kk)
                                    : (W1t + (n - 128) * 256 + 128 + kk);
            svec8 bf = *(const svec8*)bp;
            acc[t] = __builtin_amdgcn_mfma_f32_32x32x16_bf16(af, bf, acc[t], 0, 0, 0);
        }
    }
    // pack: lane (l31,hi) holds features {s*32+l31} for 16 nodes; permuted byte = l31*4+s
    #pragma unroll
    for (int r = 0; r < 16; ++r) {
        int m = (r & 3) + 8 * (r >> 2) + 4 * hi;
        int node = base + wv * 32 + m;
        if (node < N_NODES) {
            float v0 = acc[0][r] + b1v[0], v1 = acc[1][r] + b1v[1];
            float v2 = acc[2][r] + b1v[2], v3 = acc[3][r] + b1v[3];
            int q = __builtin_amdgcn_cvt_pk_fp8_f32(v0, v1, 0, false);
            q     = __builtin_amdgcn_cvt_pk_fp8_f32(v2, v3, q, true);
            *(unsigned*)(P + (size_t)node * 256 + l31 * 4) = (unsigned)q;
            int q2 = __builtin_amdgcn_cvt_pk_fp8_f32(acc[4][r], acc[5][r], 0, false);
            q2     = __builtin_amdgcn_cvt_pk_fp8_f32(acc[6][r], acc[7][r], q2, true);
            *(unsigned*)(P + (size_t)node * 256 + 128 + l31 * 4) = (unsigned)q2;
        }
    }
}

// ---- edge kernel: 16x16x32 MFMA, 16 edges/wave-iter, prefetch pipeline ----
// NATURAL register allocation ((256,2) = cap only). Rounds 5/7 proved forcing
// min-waves>natural-demand => spill => 2x regression. acc = 32 AGPR.
// P/W2f/w1s all use permuted k: P byte b <-> feature (b&3)*32 + (b>>2).
__global__ __launch_bounds__(256, 2) void egnn_edge_p2(
    const u8* __restrict__ P, const void* __restrict__ coord_diff,
    const void* __restrict__ edge_attr, const void* __restrict__ edge_index,
    const void* __restrict__ W1, const void* __restrict__ b2,
    const void* __restrict__ W3, const u16* __restrict__ W2t,
    float* __restrict__ agg, const int* __restrict__ flags)
{
    __shared__ __align__(16) u16 W2f[16384];   // 32 KB, fragment-ordered, permuted k
    __shared__ float w1s[128];                 // permuted k
    __shared__ float b2s[128];
    __shared__ float w3s[128];
    const int tid = threadIdx.x;
    const int is_bf = flags[0], is_i64 = flags[1];
    // stage W2 fragments: chunk f=(t*4+c)*64+ln; lane ln = (n=t*16+(ln&15), kg=ln>>4);
    // short j holds B[k][n] with permuted feature f = (j&3)*32 + c*8 + kg*2 + (j>>2)
    #pragma unroll
    for (int i = 0; i < 8; ++i) {
        int f = i * 256 + tid;
        int t = f >> 8, c = (f >> 6) & 3, ln = f & 63;
        int n = t * 16 + (ln & 15), kg = ln >> 4;
        pk8_u tmp;
        #pragma unroll
        for (int j = 0; j < 8; ++j) {
            int feat = (j & 3) * 32 + c * 8 + kg * 2 + (j >> 2);
            tmp.h[j] = W2t[n * 128 + feat];
        }
        *(svec8*)(&W2f[f * 8]) = tmp.s;
    }
    if (tid < 128) {
        int c = tid >> 5, kgs = (tid >> 3) & 3, d = (tid >> 2) & 1, e = tid & 3;
        int feat = e * 32 + c * 8 + kgs * 2 + d;
        w1s[tid] = ldf(W1, (size_t)256 * 128 + feat, is_bf);
        b2s[tid] = ldf(b2, tid, is_bf);
        w3s[tid] = ldf(W3, tid, is_bf);
    }
    __syncthreads();                           // last barrier; loop is wave-autonomous

    const int lane = tid & 63, wv = tid >> 6;
    const int m = lane & 15, kg = lane >> 4;   // edge-in-group, k-group
    const int wid = blockIdx.x * 4 + wv, nw = gridDim.x * 4;

    int g = wid;
    int row_c = 0, col_c = 0; float ea_c = 0.0f;
    int row_n = 0, col_n = 0; float ea_n = 0.0f;
    uvec2 p1c[4], p2c[4];
    if (g < NG16) {
        const size_t e0 = (size_t)g * 16 + m;
        row_c = ldi(edge_index, e0, is_i64);
        col_c = ldi(edge_index, (size_t)E_EDGES + e0, is_i64);
        ea_c  = ldf(edge_attr, e0, is_bf);
        const u8* pr = P + (size_t)row_c * 256 + kg * 8;
        const u8* pc = P + (size_t)col_c * 256 + 128 + kg * 8;
        #pragma unroll
        for (int s = 0; s < 4; ++s) {
            p1c[s] = *(const uvec2*)(pr + s * 32);
            p2c[s] = *(const uvec2*)(pc + s * 32);
        }
        const int gn = g + nw;
        if (gn < NG16) {
            const size_t e1 = (size_t)gn * 16 + m;
            row_n = ldi(edge_index, e1, is_i64);
            col_n = ldi(edge_index, (size_t)E_EDGES + e1, is_i64);
            ea_n  = ldf(edge_attr, e1, is_bf);
        }
    }
    for (; g < NG16; g += nw) {
        const int gn = g + nw, g2 = g + 2 * nw;
        // prefetch P(g+nw) — idx arrived last iter; in flight across this iter's compute
        uvec2 p1n[4] = {}, p2n[4] = {};
        if (gn < NG16) {
            const u8* pr = P + (size_t)row_n * 256 + kg * 8;
            const u8* pc = P + (size_t)col_n * 256 + 128 + kg * 8;
            #pragma unroll
            for (int s = 0; s < 4; ++s) {
                p1n[s] = *(const uvec2*)(pr + s * 32);
                p2n[s] = *(const uvec2*)(pc + s * 32);
            }
        }
        // prefetch idx(g+2*nw)
        int row_t = 0, col_t = 0; float ea_t = 0.0f;
        if (g2 < NG16) {
            const size_t e2 = (size_t)g2 * 16 + m;
            row_t = ldi(edge_index, e2, is_i64);
            col_t = ldi(edge_index, (size_t)E_EDGES + e2, is_i64);
            ea_t  = ldf(edge_attr, e2, is_bf);
        }
        // ---- compute on current ----
        fvec4 acc[8] = {};
        #pragma unroll
        for (int s = 0; s < 4; ++s) {
            const int k0 = s * 32 + kg * 8;
            float4 wla = *(const float4*)(&w1s[k0]);
            float4 wlb = *(const float4*)(&w1s[k0 + 4]);
            frag_u af;
            #pragma unroll
            for (int d = 0; d < 2; ++d) {
                fvec2 a01 = __builtin_amdgcn_cvt_pk_f32_fp8((int)p1c[s][d], false);
                fvec2 a23 = __builtin_amdgcn_cvt_pk_f32_fp8((int)p1c[s][d], true);
                fvec2 b01 = __builtin_amdgcn_cvt_pk_f32_fp8((int)p2c[s][d], false);
                fvec2 b23 = __builtin_amdgcn_cvt_pk_f32_fp8((int)p2c[s][d], true);
                const float* wl = d ? &wlb.x : &wla.x;
                float x0 = a01[0] + b01[0] + ea_c * wl[0];
                float x1 = a01[1] + b01[1] + ea_c * wl[1];
                float x2 = a23[0] + b23[0] + ea_c * wl[2];
                float x3 = a23[1] + b23[1] + ea_c * wl[3];
                float y0 = silu_f(x0), y1 = silu_f(x1);
                float y2 = silu_f(x2), y3 = silu_f(x3);
                af.u[d * 2 + 0] = (f2u(y0) >> 16) | (f2u(y1) & 0xFFFF0000u);
                af.u[d * 2 + 1] = (f2u(y2) >> 16) | (f2u(y3) & 0xFFFF0000u);
            }
            #pragma unroll
            for (int t = 0; t < 8; ++t) {
                svec8 bf = *(const svec8*)(&W2f[((t * 4 + s) * 64 + lane) * 8]);
                acc[t] = __builtin_amdgcn_mfma_f32_16x16x32_bf16(af.s, bf, acc[t], 0, 0, 0);
            }
        }
        // epilogue: C layout col=m(=n offset), row=kg*4+r(=edge in group)
        float s4[4] = {0.0f, 0.0f, 0.0f, 0.0f};
        #pragma unroll
        for (int t = 0; t < 8; ++t) {
            const float bb = b2s[t * 16 + m];
            const float ww = w3s[t * 16 + m];
            #pragma unroll
            for (int r = 0; r < 4; ++r)
                s4[r] += silu_f(acc[t][r] + bb) * ww;
        }
        #pragma unroll
        for (int r = 0; r < 4; ++r) {          // sum over the 16-lane col group
            s4[r] += __shfl_xor(s4[r], 1);
            s4[r] += __shfl_xor(s4[r], 2);
            s4[r] += __shfl_xor(s4[r], 4);
            s4[r] += __shfl_xor(s4[r], 8);
        }
        const int r2 = __shfl(row_c, kg * 4 + m);   // row idx of edge g*16+kg*4+m
        if (m < 4) {
            const float phi = s4[m];
            const size_t eg = (size_t)g * 16 + kg * 4 + m;
            const float cx = ldf(coord_diff, eg * 3 + 0, is_bf);
            const float cy = ldf(coord_diff, eg * 3 + 1, is_bf);
            const float cz = ldf(coord_diff, eg * 3 + 2, is_bf);
            atomicAdd(&agg[r2 * 3 + 0], cx * phi);
            atomicAdd(&agg[r2 * 3 + 1], cy * phi);
            atomicAdd(&agg[r2 * 3 + 2], cz * phi);
        }
        // rotate pipeline
        #pragma unroll
        for (int s = 0; s < 4; ++s) { p1c[s] = p1n[s]; p2c[s] = p2n[s]; }
        row_c = row_n; col_c = col_n; ea_c = ea_n;
        row_n = row_t; col_n = col_t; ea_n = ea_t;
    }
}

// ================= fallback (round-3, verified) when ws too small =================
__global__ __launch_bounds__(256, 2) void egnn_edge_kernel(
    const void* __restrict__ h, const void* __restrict__ coord_diff,
    const void* __restrict__ edge_attr, const void* __restrict__ edge_index,
    const void* __restrict__ W1, const void* __restrict__ b1,
    const void* __restrict__ b2, const void* __restrict__ W3,
    const u16* __restrict__ W1t, const u16* __restrict__ W2t,
    float* __restrict__ agg, const int* __restrict__ flags)
{
    __shared__ __align__(16) u16 Xs[BE * XS_STRIDE];
    __shared__ int   rows_s[BE];
    __shared__ int   cols_s[BE];
    __shared__ float ea_s[BE];
    __shared__ float b1_s[HID], b2_s[HID], w1l_s[HID], w3_s[HID];

    const int tid = threadIdx.x;
    const int e0  = blockIdx.x * BE;
    const int is_bf  = flags[0];
    const int is_i64 = flags[1];

    if (tid < BE) {
        rows_s[tid] = ldi(edge_index, (size_t)(e0 + tid), is_i64);
        cols_s[tid] = ldi(edge_index, (size_t)(E_EDGES + e0 + tid), is_i64);
        ea_s[tid]   = ldf(edge_attr, (size_t)(e0 + tid), is_bf);
    }
    if (tid < HID) {
        b1_s[tid]  = ldf(b1, tid, is_bf);
        b2_s[tid]  = ldf(b2, tid, is_bf);
        w1l_s[tid] = ldf(W1, (size_t)256 * 128 + tid, is_bf);
        w3_s[tid]  = ldf(W3, tid, is_bf);
    }
    __syncthreads();
    {
        const int gg = tid >> 4, c = tid & 15;
        #pragma unroll
        for (int it = 0; it < 16; ++it) {
            int hr = it * 16 + gg;
            int e = hr >> 1, half = hr & 1;
            int src = half ? cols_s[e] : rows_s[e];
            svec8 v;
            if (is_bf) {
                v = *(const svec8*)((const u16*)h + (size_t)src * HID + c * 8);
            } else {
                const float* hf = (const float*)h + (size_t)src * HID + c * 8;
                float4 va = *(const float4*)hf;
                float4 vb = *(const float4*)(hf + 4);
                v[0] = (short)f2bf(va.x); v[1] = (short)f2bf(va.y);
                v[2] = (short)f2bf(va.z); v[3] = (short)f2bf(va.w);
                v[4] = (short)f2bf(vb.x); v[5] = (short)f2bf(vb.y);
                v[6] = (short)f2bf(vb.z); v[7] = (short)f2bf(vb.w);
            }
            *(svec8*)(&Xs[e * XS_STRIDE + half * 128 + c * 8]) = v;
        }
    }
    __syncthreads();
    const int lane = tid & 63;
    const int wv   = tid >> 6;
    const int l31  = lane & 31, hi = lane >> 5;
    const int col  = wv * 32 + l31;

    fvec16 acc[4] = {};
    for (int ks = 0; ks < 16; ++ks) {
        const int kk = ks * 16 + hi * 8;
        svec8 bfrag = *(const svec8*)(W1t + col * 256 + kk);
        #pragma unroll
        for (int mt = 0; mt < 4; ++mt) {
            svec8 afrag = *(const svec8*)(&Xs[(mt * 32 + l31) * XS_STRIDE + kk]);
            acc[mt] = __builtin_amdgcn_mfma_f32_32x32x16_bf16(afrag, bfrag, acc[mt], 0, 0, 0);
        }
    }
    __syncthreads();
    u16* Ys = Xs;
    #pragma unroll
    for (int mt = 0; mt < 4; ++mt)
        #pragma unroll
        for (int r = 0; r < 16; ++r) {
            int row = mt * 32 + (r & 3) + 8 * (r >> 2) + 4 * hi;
            float v = acc[mt][r] + ea_s[row] * w1l_s[col] + b1_s[col];
            Ys[row * YS_STRIDE + col] = f2bf(silu_f(v));
        }
    __syncthreads();
    fvec16 acc2[4] = {};
    for (int ks = 0; ks < 8; ++ks) {
        const int kk = ks * 16 + hi * 8;
        svec8 bfrag = *(const svec8*)(W2t + col * 128 + kk);
        #pragma unroll
        for (int mt = 0; mt < 4; ++mt) {
            svec8 afrag = *(const svec8*)(&Ys[(mt * 32 + l31) * YS_STRIDE + kk]);
            acc2[mt] = __builtin_amdgcn_mfma_f32_32x32x16_bf16(afrag, bfrag, acc2[mt], 0, 0, 0);
        }
    }
    __syncthreads();
    #pragma unroll
    for (int mt = 0; mt < 4; ++mt)
        #pragma unroll
        for (int r = 0; r < 16; ++r) {
            int row = mt * 32 + (r & 3) + 8 * (r >> 2) + 4 * hi;
            float v = acc2[mt][r] + b2_s[col];
            Ys[row * YS_STRIDE + col] = f2bf(silu_f(v));
        }
    __syncthreads();
    if (tid < BE) {
        const int e = tid;
        float phi = 0.0f;
        #pragma unroll
        for (int j = 0; j < 16; ++j) {
            svec8 x = *(const svec8*)(&Ys[e * YS_STRIDE + j * 8]);
            #pragma unroll
            for (int t = 0; t < 8; ++t)
                phi += bf2f((u16)x[t]) * w3_s[j * 8 + t];
        }
        const size_t ei = (size_t)(e0 + e);
        const int r = rows_s[e];
        atomicAdd(&agg[r * 3 + 0], ldf(coord_diff, ei * 3 + 0, is_bf) * phi);
        atomicAdd(&agg[r * 3 + 1], ldf(coord_diff, ei * 3 + 1, is_bf) * phi);
        atomicAdd(&agg[r * 3 + 2], ldf(coord_diff, ei * 3 + 2, is_bf) * phi);
    }
}

// ---- finalize: out = coord + agg/100, written in the input float dtype ----
__global__ void finalize_kernel(const void* __restrict__ coord,
                                const float* __restrict__ agg,
                                void* __restrict__ out,
                                const int* __restrict__ flags) {
    const int is_bf = flags[0];
    int i = blockIdx.x * blockDim.x + threadIdx.x;
    if (i < N_NODES * 3) {
        float v = ldf(coord, i, is_bf) + agg[i] * 0.01f;
        if (is_bf) ((u16*)out)[i] = f2bf(v);
        else       ((float*)out)[i] = v;
    }
}

extern "C" void kernel_launch(void* const* d_in, const int* in_sizes, int n_in,
                              void* d_out, int out_size, void* d_ws, size_t ws_size,
                              hipStream_t stream) {
    const void* h          = d_in[0];
    const void* coord      = d_in[1];
    const void* coord_diff = d_in[2];
    // d_in[3] = coord_cross (unused)
    const void* edge_attr  = d_in[4];
    const void* edge_index = d_in[5];
    const void* W1 = d_in[6];
    const void* b1 = d_in[7];
    const void* W2 = d_in[8];
    const void* b2 = d_in[9];
    const void* W3 = d_in[10];

    char* ws    = (char*)d_ws;
    float* agg  = (float*)ws;                        // 600000 B
    u16* W1t    = (u16*)(ws + 600064);               // 65536 B
    u16* W2t    = (u16*)(ws + 665600);               // 32768 B
    int* flags  = (int*)(ws + 698368);               // 16 B
    u8* P       = (u8*)(ws + 698880);                // 12,800,000 B (fp8, permuted k)
    const size_t NEED = 698880 + (size_t)N_NODES * 256;

    detect_kernel<<<dim3(1), dim3(256), 0, stream>>>(h, edge_index, flags);
    hipMemsetAsync(agg, 0, N_NODES * 3 * sizeof(float), stream);
    transpose_w<<<dim3(128), dim3(256), 0, stream>>>(W1, W2, W1t, W2t, flags);

    if (ws_size >= NEED) {
        precompute_p<<<dim3((N_NODES + 127) / 128), dim3(256), 0, stream>>>(
            h, b1, W1t, flags, P);
        egnn_edge_p2<<<dim3(768), dim3(256), 0, stream>>>(
            P, coord_diff, edge_attr, edge_index, W1, b2, W3, W2t, agg, flags);
    } else {
        egnn_edge_kernel<<<dim3(E_EDGES / BE), dim3(256), 0, stream>>>(
            h, coord_diff, edge_attr, edge_index, W1, b1, b2, W3, W1t, W2t, agg, flags);
    }
    finalize_kernel<<<dim3((N_NODES * 3 + 255) / 256), dim3(256), 0, stream>>>(coord, agg, d_out, flags);
}